// Round 10
// baseline (1409.901 us; speedup 1.0000x reference)
//
#include <hip/hip_runtime.h>
#include <stdint.h>

typedef float4 __attribute__((may_alias)) float4a;
typedef unsigned int u32;
typedef unsigned long long u64;

// ws float layout: [0] loss, [1] sum(ema_cs),
// [16,16+K) e2 | [16+K,+K) counts | [16+2K,+K*64) emb sums | then N u64 slots
#define WS_LOSS 0
#define WS_SEMA 1
#define WS_HDR  16

__global__ void k_sig(float* o, float v) { o[0] = v; }

__device__ __forceinline__ float sq_nofuse(float x) {
  float p = x * x;
  __asm__("" : "+v"(p));   // block ffp-contract fusing (numpy rounds the square)
  return p;
}

// numpy pairwise_sum of squares, n=64 contiguous fp32: 8 accumulators + fixed
// combine tree, STREAMING (only ~16 live temps -> no spill).
__device__ __forceinline__ float z2_np64(const float* v) {
  float r0 = sq_nofuse(v[0]), r1 = sq_nofuse(v[1]);
  float r2 = sq_nofuse(v[2]), r3 = sq_nofuse(v[3]);
  float r4 = sq_nofuse(v[4]), r5 = sq_nofuse(v[5]);
  float r6 = sq_nofuse(v[6]), r7 = sq_nofuse(v[7]);
  #pragma unroll
  for (int i = 8; i < 64; i += 8) {
    r0 += sq_nofuse(v[i + 0]); r1 += sq_nofuse(v[i + 1]);
    r2 += sq_nofuse(v[i + 2]); r3 += sq_nofuse(v[i + 3]);
    r4 += sq_nofuse(v[i + 4]); r5 += sq_nofuse(v[i + 5]);
    r6 += sq_nofuse(v[i + 6]); r7 += sq_nofuse(v[i + 7]);
  }
  return ((r0 + r1) + (r2 + r3)) + ((r4 + r5) + (r6 + r7));
}

__global__ __launch_bounds__(256) void k_prep(const float* __restrict__ cb,
                                              const float* __restrict__ ecs,
                                              float* __restrict__ ws, int K) {
  const int k = blockIdx.x * 256 + threadIdx.x;   // grid covers exactly K rows
  const float* e = cb + ((size_t)k << 6);
  ws[WS_HDR + k] = z2_np64(e);                    // e2[k], np-fp32-exact

  float v = ecs[k];
  #pragma unroll
  for (int o = 32; o; o >>= 1) v += __shfl_xor(v, o, 64);
  if ((threadIdx.x & 63) == 0) atomicAdd(&ws[WS_SEMA], v);
}

// one j-step: 8 rows x 8 codes, direct float4 components (no local arrays)
#define ROWFMA(R, ZV) \
  acc[R][0] = __builtin_fmaf(el.x, ZV, acc[R][0]); \
  acc[R][1] = __builtin_fmaf(el.y, ZV, acc[R][1]); \
  acc[R][2] = __builtin_fmaf(el.z, ZV, acc[R][2]); \
  acc[R][3] = __builtin_fmaf(el.w, ZV, acc[R][3]); \
  acc[R][4] = __builtin_fmaf(eh.x, ZV, acc[R][4]); \
  acc[R][5] = __builtin_fmaf(eh.y, ZV, acc[R][5]); \
  acc[R][6] = __builtin_fmaf(eh.z, ZV, acc[R][6]); \
  acc[R][7] = __builtin_fmaf(eh.w, ZV, acc[R][7]);

#define SELC(C, E2C) { \
    const int kk = kt + (C); \
    _Pragma("unroll") \
    for (int r = 0; r < 8; ++r) { \
      const float d = __builtin_fmaf(-2.0f, acc[r][C], z2r[r] + (E2C)); \
      if (d < best[r]) { best[r] = d; bk[r] = kk; } \
    } \
  }

// GEMM-fragment distance scan, 8x8 fragments (R8-verified compute), 128-row
// block, eb staged in 32-j half-tiles -> 50KB LDS -> 3 blocks/CU. Barriers
// double but only sync within a block; co-resident blocks cover the stalls.
// acc chains ascend j across the two halves = bit-identical np/BLAS order.
__global__ __launch_bounds__(256) void k_main(const float* __restrict__ z,
                                              const float* __restrict__ cb,
                                              const float* __restrict__ e2s,
                                              u64* __restrict__ slots,
                                              int N, int K) {
  __shared__ float zT[64][128];        // zT[j][row], staged once (32KB)
  __shared__ float eb[32][128];        // eT[j-of-half][code] (16KB)
  __shared__ float z2p[128][4];        // per-row np-tree partials (2KB)

  const int tid  = threadIdx.x;
  const int lane = tid & 63;
  const int w    = tid >> 6;
  const int g    = lane & 15;                       // row-quad group
  const int b8   = (((w << 2) | (lane >> 4)) << 3); // code-frag base 0..120
  const int rowbase = blockIdx.x * 128;
  const int nt   = K >> 7;                          // tiles of 128 codes

  // staging role: thread covers (code sc, j-16-chunk h of the current half)
  const int sc = tid & 127;
  const int h  = tid >> 7;

  // ---- stage tile0/half0 loads first (latency hidden under z staging)
  float4 s[4];
  {
    const float4a* sp = (const float4a*)(cb + ((size_t)sc << 6) + (h << 4));
    #pragma unroll
    for (int i = 0; i < 4; ++i) s[i] = sp[i];
  }

  // ---- prologue: stage zT (transposed) + z2 partials (R8-verified pattern)
  {
    const int jh = h << 5;
    const float4a* src = (const float4a*)(z + ((size_t)(rowbase + sc) << 6) + jh);
    float4 zs[8];
    #pragma unroll
    for (int i = 0; i < 8; ++i) zs[i] = src[i];
    #pragma unroll
    for (int i = 0; i < 8; ++i) {
      zT[jh + 4*i + 0][sc] = zs[i].x;
      zT[jh + 4*i + 1][sc] = zs[i].y;
      zT[jh + 4*i + 2][sc] = zs[i].z;
      zT[jh + 4*i + 3][sc] = zs[i].w;
    }
    // z2 partials: np-tree accumulators r_{4h..4h+3} -> s_{2h}, s_{2h+1};
    // final (s0+s1)+(s2+s3) reproduces z2_np64's combine tree bit-exactly.
    const float* vr = z + ((size_t)(rowbase + sc) << 6) + 4*h;
    float ra = sq_nofuse(vr[0]), rb = sq_nofuse(vr[1]);
    float rc = sq_nofuse(vr[2]), rd = sq_nofuse(vr[3]);
    #pragma unroll
    for (int i = 8; i < 64; i += 8) {
      ra += sq_nofuse(vr[i + 0]); rb += sq_nofuse(vr[i + 1]);
      rc += sq_nofuse(vr[i + 2]); rd += sq_nofuse(vr[i + 3]);
    }
    z2p[sc][2*h + 0] = ra + rb;
    z2p[sc][2*h + 1] = rc + rd;
  }
  __syncthreads();                      // zT, z2p visible (= bar1 of (0,0))

  // per-lane row constants: r<4 -> row 4g+r ; r>=4 -> row 64+4g+(r-4)
  float z2r[8];
  #pragma unroll
  for (int i = 0; i < 4; ++i) {
    { const float4 p = *(const float4a*)&z2p[4*g + i][0];
      z2r[i]     = (p.x + p.y) + (p.z + p.w); }
    { const float4 p = *(const float4a*)&z2p[64 + 4*g + i][0];
      z2r[4 + i] = (p.x + p.y) + (p.z + p.w); }
  }

  float best[8]; int bk[8];
  #pragma unroll
  for (int r = 0; r < 8; ++r) { best[r] = 3.0e38f; bk[r] = 0; }

  for (int t = 0; t < nt; ++t) {
    float acc[8][8];
    #pragma unroll
    for (int r = 0; r < 8; ++r)
      #pragma unroll
      for (int c = 0; c < 8; ++c) acc[r][c] = 0.f;

    #pragma unroll 1
    for (int half = 0; half < 2; ++half) {
      // s holds this half's e data (issued one compute-phase ago)
      #pragma unroll
      for (int i = 0; i < 4; ++i) {     // transposed write, 2-way banks (free)
        eb[(h << 4) + 4*i + 0][sc] = s[i].x;
        eb[(h << 4) + 4*i + 1][sc] = s[i].y;
        eb[(h << 4) + 4*i + 2][sc] = s[i].z;
        eb[(h << 4) + 4*i + 3][sc] = s[i].w;
      }
      __syncthreads();                  // bar2: eb half ready

      // issue next half's loads NOW: full 32-j compute covers the latency,
      // and the trailing barrier's vmcnt-drain then costs nothing.
      const bool more = (t + 1 < nt) | (half == 0);
      if (more) {
        const int nt128 = (half == 0) ? t * 128 : (t + 1) * 128;
        const int njb   = (half == 0) ? 32 : 0;
        const float4a* sp =
            (const float4a*)(cb + ((size_t)(nt128 + sc) << 6) + njb + (h << 4));
        #pragma unroll
        for (int i = 0; i < 4; ++i) s[i] = sp[i];
      }

      const int jb = half << 5;
      #pragma unroll 4
      for (int jj = 0; jj < 32; ++jj) {
        const float4 zl = *(const float4a*)&zT[jb + jj][4*g];
        const float4 zh = *(const float4a*)&zT[jb + jj][64 + 4*g];
        const float4 el = *(const float4a*)&eb[jj][b8];
        const float4 eh = *(const float4a*)&eb[jj][b8 + 4];
        ROWFMA(0, zl.x) ROWFMA(1, zl.y) ROWFMA(2, zl.z) ROWFMA(3, zl.w)
        ROWFMA(4, zh.x) ROWFMA(5, zh.y) ROWFMA(6, zh.z) ROWFMA(7, zh.w)
      }
      __syncthreads();                  // bar1: all reads of this half done
    }

    // selection per 128-code tile: lane's codes ascend (c, then t)
    // -> strict < = first-min-wins (R8-verified)
    const float4 e2lo = *(const float4a*)(e2s + t * 128 + b8);      // L1-hot
    const float4 e2hi = *(const float4a*)(e2s + t * 128 + b8 + 4);
    const int kt = t * 128 + b8;
    SELC(0, e2lo.x) SELC(1, e2lo.y) SELC(2, e2lo.z) SELC(3, e2lo.w)
    SELC(4, e2hi.x) SELC(5, e2hi.y) SELC(6, e2hi.z) SELC(7, e2hi.w)
  }

  // ---- cross-lane merge over the 4 code-groups (lanes g, g+16, g+32, g+48):
  // lexicographic (d, k): equal d -> smaller k (global first-min)
  #pragma unroll
  for (int off = 16; off <= 32; off <<= 1) {
    #pragma unroll
    for (int r = 0; r < 8; ++r) {
      const float pd = __shfl_xor(best[r], off, 64);
      const int   pk = __shfl_xor(bk[r], off, 64);
      if (pd < best[r] || (pd == best[r] && pk < bk[r])) { best[r] = pd; bk[r] = pk; }
    }
  }
  // ---- cross-wave merge via packed atomicMin (distances > 0)
  if (lane < 16) {
    #pragma unroll
    for (int r = 0; r < 8; ++r) {
      const int row = (r < 4) ? (4 * lane + r) : (64 + 4 * lane + (r - 4));
      atomicMin(&slots[rowbase + row],
                ((u64)__float_as_uint(best[r]) << 32) | (u32)bk[r]);
    }
  }
}

// epilogue: read winner, write index+quantized, loss, EMA scatter
__global__ __launch_bounds__(256) void k_post(const float* __restrict__ z,
                                              const float* __restrict__ cb,
                                              const u64* __restrict__ slots,
                                              float* __restrict__ ws,
                                              float* __restrict__ o,
                                              int N, int K) {
  const int r = blockIdx.x * 256 + threadIdx.x;
  const int bk = (int)(u32)(slots[r] & 0xFFFFFFFFull);
  const size_t base = (size_t)N << 6;
  o[base + 1 + (size_t)r] = (float)bk;

  const float4a* zr = (const float4a*)(z + ((size_t)r << 6));
  const float4a* qr = (const float4a*)(cb + ((size_t)bk << 6));
  float4a* dst = (float4a*)(o + ((size_t)r << 6));
  float zbuf[64];
  float lsum = 0.f;
  #pragma unroll
  for (int t = 0; t < 16; ++t) {
    const float4 zw = zr[t];
    const float4 qw = qr[t];
    float4 out;
    float d;
    d = zw.x - qw.x; lsum = __builtin_fmaf(d, d, lsum); out.x = zw.x + (qw.x - zw.x);
    d = zw.y - qw.y; lsum = __builtin_fmaf(d, d, lsum); out.y = zw.y + (qw.y - zw.y);
    d = zw.z - qw.z; lsum = __builtin_fmaf(d, d, lsum); out.z = zw.z + (qw.z - zw.z);
    d = zw.w - qw.w; lsum = __builtin_fmaf(d, d, lsum); out.w = zw.w + (qw.w - zw.w);
    dst[t] = out;
    zbuf[4*t] = zw.x; zbuf[4*t+1] = zw.y; zbuf[4*t+2] = zw.z; zbuf[4*t+3] = zw.w;
  }

  #pragma unroll
  for (int s = 32; s; s >>= 1) lsum += __shfl_xor(lsum, s, 64);
  if ((threadIdx.x & 63) == 0) atomicAdd(ws + WS_LOSS, lsum);

  atomicAdd(ws + WS_HDR + K + bk, 1.0f);
  float* emb = ws + WS_HDR + 2 * K + ((size_t)bk << 6);
  #pragma unroll
  for (int j = 0; j < 64; ++j) atomicAdd(emb + j, zbuf[j]);
}

__global__ __launch_bounds__(256) void k_fin(const float* __restrict__ ecs,
                                             const float* __restrict__ ees,
                                             const float* __restrict__ ws,
                                             float* __restrict__ o,
                                             int N, int K, float lossmul) {
  const int KD = K << 6;
  const int idx = blockIdx.x * 256 + threadIdx.x;
  if (idx >= KD) return;
  const int k = idx >> 6;
  const int j = idx & 63;
  const size_t base = (size_t)N << 6;

  const float n = 0.99f * ws[WS_SEMA] + 0.01f * (float)N;
  const float cs_new = 0.99f * ecs[k] + 0.01f * ws[WS_HDR + K + k];
  const float smoothed = (cs_new + 1e-5f) / (n + (float)K * 1e-5f) * n;
  const float es_new = 0.99f * ees[idx] + 0.01f * ws[WS_HDR + 2 * K + idx];

  const size_t es_base = base + 1 + (size_t)N + (size_t)K;
  o[es_base + (size_t)idx] = es_new;
  o[es_base + (size_t)KD + (size_t)idx] = es_new / smoothed;
  if (j == 0)   o[base + 1 + (size_t)N + (size_t)k] = cs_new;
  if (idx == 0) o[base] = ws[WS_LOSS] * lossmul;
}

extern "C" void kernel_launch(void* const* d_in, const int* in_sizes, int n_in,
                              void* d_out, int out_size, void* d_ws, size_t ws_size,
                              hipStream_t stream) {
  float* o = (float*)d_out;
  const float* z   = (const float*)d_in[0];
  const float* cb  = (const float*)d_in[1];
  const float* ecs = (const float*)d_in[2];
  const float* ees = (const float*)d_in[3];
  float* ws = (float*)d_ws;

  const long long ND  = (n_in > 0) ? (long long)in_sizes[0] : 0;
  const long long KD  = (n_in > 1) ? (long long)in_sizes[1] : 0;
  const long long K   = (n_in > 2) ? (long long)in_sizes[2] : 0;
  const long long KD2 = (n_in > 3) ? (long long)in_sizes[3] : 0;
  const long long D   = (K > 0) ? KD / K : 0;
  const long long N   = (D > 0) ? ND / D : 0;

  const long long ws_floats = 16 + 2 * K + KD + 2 * N;  // slots = N u64 at tail

  float sig = 0.f;
  if (n_in != 4)                          sig = 1e4f * (float)n_in;
  else if (K <= 0 || KD % K != 0)         sig = 2.5e7f;
  else if (D != 64)                       sig = 1e7f + 1e4f * (float)D;
  else if (KD2 != KD)                     sig = 2e7f;
  else if (ND % 64 != 0 || N % 512 != 0)  sig = 3e7f;
  else if (K % 256 != 0)                  sig = 5e7f;
  else if ((long long)out_size != ND + 1 + N + K + 2 * KD)
                                          sig = (float)out_size;
  else if (ws_size < (size_t)ws_floats * sizeof(float))
                                          sig = 7e6f;
  if (sig != 0.f) { k_sig<<<1, 1, 0, stream>>>(o, sig); return; }

  u64* slots = (u64*)(ws + 16 + 2 * K + KD);      // 8-byte aligned offset
  const float lossmul = (float)(0.25 / (double)ND);

  hipMemsetAsync(ws, 0, (size_t)(16 + 2 * K + KD) * sizeof(float), stream);
  hipMemsetAsync(slots, 0xFF, (size_t)N * sizeof(u64), stream);
  k_prep<<<(int)(K / 256), 256, 0, stream>>>(cb, ecs, ws, (int)K);
  k_main<<<(int)(N / 128), 256, 0, stream>>>(z, cb, ws + WS_HDR, slots, (int)N, (int)K);
  k_post<<<(int)(N / 256), 256, 0, stream>>>(z, cb, slots, ws, o, (int)N, (int)K);
  k_fin<<<(int)(KD / 256), 256, 0, stream>>>(ecs, ees, ws, o, (int)N, (int)K, lossmul);
}

// Round 11
// 942.565 us; speedup vs baseline: 1.4958x; 1.4958x over previous
//
#include <hip/hip_runtime.h>
#include <stdint.h>

typedef float4 __attribute__((may_alias)) float4a;
typedef unsigned int u32;
typedef unsigned long long u64;

// ws float layout: [0] loss, [1] sum(ema_cs),
// [16,16+K) e2 | [16+K,+K) counts | [16+2K,+K*64) emb sums | then N u64 slots
// slots region is reused AFTER k_post as u32: [0,N) rowlist | [N,N+K) offs | [N+K,N+2K) cursor
#define WS_LOSS 0
#define WS_SEMA 1
#define WS_HDR  16

__global__ void k_sig(float* o, float v) { o[0] = v; }

__device__ __forceinline__ float sq_nofuse(float x) {
  float p = x * x;
  __asm__("" : "+v"(p));   // block ffp-contract fusing (numpy rounds the square)
  return p;
}

// numpy pairwise_sum of squares, n=64 contiguous fp32: 8 accumulators + fixed
// combine tree, STREAMING (only ~16 live temps -> no spill).
__device__ __forceinline__ float z2_np64(const float* v) {
  float r0 = sq_nofuse(v[0]), r1 = sq_nofuse(v[1]);
  float r2 = sq_nofuse(v[2]), r3 = sq_nofuse(v[3]);
  float r4 = sq_nofuse(v[4]), r5 = sq_nofuse(v[5]);
  float r6 = sq_nofuse(v[6]), r7 = sq_nofuse(v[7]);
  #pragma unroll
  for (int i = 8; i < 64; i += 8) {
    r0 += sq_nofuse(v[i + 0]); r1 += sq_nofuse(v[i + 1]);
    r2 += sq_nofuse(v[i + 2]); r3 += sq_nofuse(v[i + 3]);
    r4 += sq_nofuse(v[i + 4]); r5 += sq_nofuse(v[i + 5]);
    r6 += sq_nofuse(v[i + 6]); r7 += sq_nofuse(v[i + 7]);
  }
  return ((r0 + r1) + (r2 + r3)) + ((r4 + r5) + (r6 + r7));
}

__global__ __launch_bounds__(256) void k_prep(const float* __restrict__ cb,
                                              const float* __restrict__ ecs,
                                              float* __restrict__ ws, int K) {
  const int k = blockIdx.x * 256 + threadIdx.x;   // grid covers exactly K rows
  const float* e = cb + ((size_t)k << 6);
  ws[WS_HDR + k] = z2_np64(e);                    // e2[k], np-fp32-exact

  float v = ecs[k];
  #pragma unroll
  for (int o = 32; o; o >>= 1) v += __shfl_xor(v, o, 64);
  if ((threadIdx.x & 63) == 0) atomicAdd(&ws[WS_SEMA], v);
}

// one j-step: 8 rows x 8 codes, direct float4 components (no local arrays)
#define ROWFMA(R, ZV) \
  acc[R][0] = __builtin_fmaf(el.x, ZV, acc[R][0]); \
  acc[R][1] = __builtin_fmaf(el.y, ZV, acc[R][1]); \
  acc[R][2] = __builtin_fmaf(el.z, ZV, acc[R][2]); \
  acc[R][3] = __builtin_fmaf(el.w, ZV, acc[R][3]); \
  acc[R][4] = __builtin_fmaf(eh.x, ZV, acc[R][4]); \
  acc[R][5] = __builtin_fmaf(eh.y, ZV, acc[R][5]); \
  acc[R][6] = __builtin_fmaf(eh.z, ZV, acc[R][6]); \
  acc[R][7] = __builtin_fmaf(eh.w, ZV, acc[R][7]);

#define SELC(C, E2C) { \
    const int kk = kt + (C); \
    _Pragma("unroll") \
    for (int r = 0; r < 8; ++r) { \
      const float d = __builtin_fmaf(-2.0f, acc[r][C], z2r[r] + (E2C)); \
      if (d < best[r]) { best[r] = d; bk[r] = kk; } \
    } \
  }

// GEMM-fragment distance scan, 8x8 fragments, 128-row block, eb in 32-j
// half-tiles -> 50KB LDS -> 3 blocks/CU. (R10-verified, 855us plateau.)
__global__ __launch_bounds__(256) void k_main(const float* __restrict__ z,
                                              const float* __restrict__ cb,
                                              const float* __restrict__ e2s,
                                              u64* __restrict__ slots,
                                              int N, int K) {
  __shared__ float zT[64][128];        // zT[j][row], staged once (32KB)
  __shared__ float eb[32][128];        // eT[j-of-half][code] (16KB)
  __shared__ float z2p[128][4];        // per-row np-tree partials (2KB)

  const int tid  = threadIdx.x;
  const int lane = tid & 63;
  const int w    = tid >> 6;
  const int g    = lane & 15;                       // row-quad group
  const int b8   = (((w << 2) | (lane >> 4)) << 3); // code-frag base 0..120
  const int rowbase = blockIdx.x * 128;
  const int nt   = K >> 7;                          // tiles of 128 codes

  // staging role: thread covers (code sc, j-16-chunk h of the current half)
  const int sc = tid & 127;
  const int h  = tid >> 7;

  // ---- stage tile0/half0 loads first (latency hidden under z staging)
  float4 s[4];
  {
    const float4a* sp = (const float4a*)(cb + ((size_t)sc << 6) + (h << 4));
    #pragma unroll
    for (int i = 0; i < 4; ++i) s[i] = sp[i];
  }

  // ---- prologue: stage zT (transposed) + z2 partials (R8-verified pattern)
  {
    const int jh = h << 5;
    const float4a* src = (const float4a*)(z + ((size_t)(rowbase + sc) << 6) + jh);
    float4 zs[8];
    #pragma unroll
    for (int i = 0; i < 8; ++i) zs[i] = src[i];
    #pragma unroll
    for (int i = 0; i < 8; ++i) {
      zT[jh + 4*i + 0][sc] = zs[i].x;
      zT[jh + 4*i + 1][sc] = zs[i].y;
      zT[jh + 4*i + 2][sc] = zs[i].z;
      zT[jh + 4*i + 3][sc] = zs[i].w;
    }
    // z2 partials: np-tree accumulators r_{4h..4h+3} -> s_{2h}, s_{2h+1};
    // final (s0+s1)+(s2+s3) reproduces z2_np64's combine tree bit-exactly.
    const float* vr = z + ((size_t)(rowbase + sc) << 6) + 4*h;
    float ra = sq_nofuse(vr[0]), rb = sq_nofuse(vr[1]);
    float rc = sq_nofuse(vr[2]), rd = sq_nofuse(vr[3]);
    #pragma unroll
    for (int i = 8; i < 64; i += 8) {
      ra += sq_nofuse(vr[i + 0]); rb += sq_nofuse(vr[i + 1]);
      rc += sq_nofuse(vr[i + 2]); rd += sq_nofuse(vr[i + 3]);
    }
    z2p[sc][2*h + 0] = ra + rb;
    z2p[sc][2*h + 1] = rc + rd;
  }
  __syncthreads();                      // zT, z2p visible

  // per-lane row constants: r<4 -> row 4g+r ; r>=4 -> row 64+4g+(r-4)
  float z2r[8];
  #pragma unroll
  for (int i = 0; i < 4; ++i) {
    { const float4 p = *(const float4a*)&z2p[4*g + i][0];
      z2r[i]     = (p.x + p.y) + (p.z + p.w); }
    { const float4 p = *(const float4a*)&z2p[64 + 4*g + i][0];
      z2r[4 + i] = (p.x + p.y) + (p.z + p.w); }
  }

  float best[8]; int bk[8];
  #pragma unroll
  for (int r = 0; r < 8; ++r) { best[r] = 3.0e38f; bk[r] = 0; }

  for (int t = 0; t < nt; ++t) {
    float acc[8][8];
    #pragma unroll
    for (int r = 0; r < 8; ++r)
      #pragma unroll
      for (int c = 0; c < 8; ++c) acc[r][c] = 0.f;

    #pragma unroll 1
    for (int half = 0; half < 2; ++half) {
      // s holds this half's e data (issued one compute-phase ago)
      #pragma unroll
      for (int i = 0; i < 4; ++i) {     // transposed write, 2-way banks (free)
        eb[(h << 4) + 4*i + 0][sc] = s[i].x;
        eb[(h << 4) + 4*i + 1][sc] = s[i].y;
        eb[(h << 4) + 4*i + 2][sc] = s[i].z;
        eb[(h << 4) + 4*i + 3][sc] = s[i].w;
      }
      __syncthreads();                  // eb half ready

      // issue next half's loads NOW: 32-j compute covers the latency
      const bool more = (t + 1 < nt) | (half == 0);
      if (more) {
        const int nt128 = (half == 0) ? t * 128 : (t + 1) * 128;
        const int njb   = (half == 0) ? 32 : 0;
        const float4a* sp =
            (const float4a*)(cb + ((size_t)(nt128 + sc) << 6) + njb + (h << 4));
        #pragma unroll
        for (int i = 0; i < 4; ++i) s[i] = sp[i];
      }

      const int jb = half << 5;
      #pragma unroll 4
      for (int jj = 0; jj < 32; ++jj) {
        const float4 zl = *(const float4a*)&zT[jb + jj][4*g];
        const float4 zh = *(const float4a*)&zT[jb + jj][64 + 4*g];
        const float4 el = *(const float4a*)&eb[jj][b8];
        const float4 eh = *(const float4a*)&eb[jj][b8 + 4];
        ROWFMA(0, zl.x) ROWFMA(1, zl.y) ROWFMA(2, zl.z) ROWFMA(3, zl.w)
        ROWFMA(4, zh.x) ROWFMA(5, zh.y) ROWFMA(6, zh.z) ROWFMA(7, zh.w)
      }
      __syncthreads();                  // all reads of this half done
    }

    // selection per 128-code tile: lane's codes ascend (c, then t)
    // -> strict < = first-min-wins
    const float4 e2lo = *(const float4a*)(e2s + t * 128 + b8);      // L1-hot
    const float4 e2hi = *(const float4a*)(e2s + t * 128 + b8 + 4);
    const int kt = t * 128 + b8;
    SELC(0, e2lo.x) SELC(1, e2lo.y) SELC(2, e2lo.z) SELC(3, e2lo.w)
    SELC(4, e2hi.x) SELC(5, e2hi.y) SELC(6, e2hi.z) SELC(7, e2hi.w)
  }

  // ---- cross-lane merge over the 4 code-groups: lexicographic (d, k)
  #pragma unroll
  for (int off = 16; off <= 32; off <<= 1) {
    #pragma unroll
    for (int r = 0; r < 8; ++r) {
      const float pd = __shfl_xor(best[r], off, 64);
      const int   pk = __shfl_xor(bk[r], off, 64);
      if (pd < best[r] || (pd == best[r] && pk < bk[r])) { best[r] = pd; bk[r] = pk; }
    }
  }
  // ---- cross-wave merge via packed atomicMin (distances > 0)
  if (lane < 16) {
    #pragma unroll
    for (int r = 0; r < 8; ++r) {
      const int row = (r < 4) ? (4 * lane + r) : (64 + 4 * lane + (r - 4));
      atomicMin(&slots[rowbase + row],
                ((u64)__float_as_uint(best[r]) << 32) | (u32)bk[r]);
    }
  }
}

// epilogue: read winner, write index+quantized, loss, counts (NO emb atomics)
__global__ __launch_bounds__(256) void k_post(const float* __restrict__ z,
                                              const float* __restrict__ cb,
                                              const u64* __restrict__ slots,
                                              float* __restrict__ ws,
                                              float* __restrict__ o,
                                              int N, int K) {
  const int r = blockIdx.x * 256 + threadIdx.x;
  const int bk = (int)(u32)(slots[r] & 0xFFFFFFFFull);
  const size_t base = (size_t)N << 6;
  o[base + 1 + (size_t)r] = (float)bk;

  const float4a* zr = (const float4a*)(z + ((size_t)r << 6));
  const float4a* qr = (const float4a*)(cb + ((size_t)bk << 6));
  float4a* dst = (float4a*)(o + ((size_t)r << 6));
  float lsum = 0.f;
  #pragma unroll
  for (int t = 0; t < 16; ++t) {
    const float4 zw = zr[t];
    const float4 qw = qr[t];
    float4 out;
    float d;
    d = zw.x - qw.x; lsum = __builtin_fmaf(d, d, lsum); out.x = zw.x + (qw.x - zw.x);
    d = zw.y - qw.y; lsum = __builtin_fmaf(d, d, lsum); out.y = zw.y + (qw.y - zw.y);
    d = zw.z - qw.z; lsum = __builtin_fmaf(d, d, lsum); out.z = zw.z + (qw.z - zw.z);
    d = zw.w - qw.w; lsum = __builtin_fmaf(d, d, lsum); out.w = zw.w + (qw.w - zw.w);
    dst[t] = out;
  }

  #pragma unroll
  for (int s = 32; s; s >>= 1) lsum += __shfl_xor(lsum, s, 64);
  if ((threadIdx.x & 63) == 0) atomicAdd(ws + WS_LOSS, lsum);

  atomicAdd(ws + WS_HDR + K + bk, 1.0f);   // counts only
}

// exclusive prefix-sum of counts -> offs, cursor (1 block)
__global__ __launch_bounds__(256) void k_scan(const float* __restrict__ counts,
                                              u32* __restrict__ offs,
                                              u32* __restrict__ cursor, int K) {
  __shared__ u32 part[256];
  const int tid = threadIdx.x;
  const int per = K >> 8;
  const int b0 = tid * per;
  u32 s = 0;
  for (int i = 0; i < per; ++i) s += (u32)counts[b0 + i];
  part[tid] = s;
  __syncthreads();
  if (tid == 0) {
    u32 run = 0;
    for (int i = 0; i < 256; ++i) { const u32 v = part[i]; part[i] = run; run += v; }
  }
  __syncthreads();
  u32 run = part[tid];
  for (int i = 0; i < per; ++i) {
    offs[b0 + i] = run;
    cursor[b0 + i] = run;
    run += (u32)counts[b0 + i];
  }
}

// scatter row ids into per-code buckets
__global__ __launch_bounds__(256) void k_scat(const float* __restrict__ idxs,
                                              u32* __restrict__ cursor,
                                              u32* __restrict__ rowlist, int N) {
  const int r = blockIdx.x * 256 + threadIdx.x;
  const int bk = (int)idxs[r];
  const u32 pos = atomicAdd(&cursor[bk], 1u);
  rowlist[pos] = (u32)r;
}

// per-code gather sum: one wave per code, lane j sums column j. Plain store.
__global__ __launch_bounds__(256) void k_emb(const float* __restrict__ z,
                                             const float* __restrict__ counts,
                                             const u32* __restrict__ offs,
                                             const u32* __restrict__ rowlist,
                                             float* __restrict__ emb, int K) {
  const int lane = threadIdx.x & 63;
  const int k = blockIdx.x * 4 + (threadIdx.x >> 6);
  const u32 off = offs[k];
  const u32 cnt = (u32)counts[k];
  float sum = 0.f;
  u32 i = 0;
  for (; i + 4 <= cnt; i += 4) {        // 4-deep ILP: rowids then 4 indep loads
    const u32 r0 = rowlist[off + i + 0];
    const u32 r1 = rowlist[off + i + 1];
    const u32 r2 = rowlist[off + i + 2];
    const u32 r3 = rowlist[off + i + 3];
    const float a0 = z[((size_t)r0 << 6) + lane];
    const float a1 = z[((size_t)r1 << 6) + lane];
    const float a2 = z[((size_t)r2 << 6) + lane];
    const float a3 = z[((size_t)r3 << 6) + lane];
    sum = (((sum + a0) + a1) + a2) + a3;
  }
  for (; i < cnt; ++i) {
    const u32 r0 = rowlist[off + i];
    sum += z[((size_t)r0 << 6) + lane];
  }
  emb[((size_t)k << 6) + lane] = sum;
}

__global__ __launch_bounds__(256) void k_fin(const float* __restrict__ ecs,
                                             const float* __restrict__ ees,
                                             const float* __restrict__ ws,
                                             float* __restrict__ o,
                                             int N, int K, float lossmul) {
  const int KD = K << 6;
  const int idx = blockIdx.x * 256 + threadIdx.x;
  if (idx >= KD) return;
  const int k = idx >> 6;
  const int j = idx & 63;
  const size_t base = (size_t)N << 6;

  const float n = 0.99f * ws[WS_SEMA] + 0.01f * (float)N;
  const float cs_new = 0.99f * ecs[k] + 0.01f * ws[WS_HDR + K + k];
  const float smoothed = (cs_new + 1e-5f) / (n + (float)K * 1e-5f) * n;
  const float es_new = 0.99f * ees[idx] + 0.01f * ws[WS_HDR + 2 * K + idx];

  const size_t es_base = base + 1 + (size_t)N + (size_t)K;
  o[es_base + (size_t)idx] = es_new;
  o[es_base + (size_t)KD + (size_t)idx] = es_new / smoothed;
  if (j == 0)   o[base + 1 + (size_t)N + (size_t)k] = cs_new;
  if (idx == 0) o[base] = ws[WS_LOSS] * lossmul;
}

extern "C" void kernel_launch(void* const* d_in, const int* in_sizes, int n_in,
                              void* d_out, int out_size, void* d_ws, size_t ws_size,
                              hipStream_t stream) {
  float* o = (float*)d_out;
  const float* z   = (const float*)d_in[0];
  const float* cb  = (const float*)d_in[1];
  const float* ecs = (const float*)d_in[2];
  const float* ees = (const float*)d_in[3];
  float* ws = (float*)d_ws;

  const long long ND  = (n_in > 0) ? (long long)in_sizes[0] : 0;
  const long long KD  = (n_in > 1) ? (long long)in_sizes[1] : 0;
  const long long K   = (n_in > 2) ? (long long)in_sizes[2] : 0;
  const long long KD2 = (n_in > 3) ? (long long)in_sizes[3] : 0;
  const long long D   = (K > 0) ? KD / K : 0;
  const long long N   = (D > 0) ? ND / D : 0;

  const long long ws_floats = 16 + 2 * K + KD + 2 * N;  // slots = N u64 at tail

  float sig = 0.f;
  if (n_in != 4)                          sig = 1e4f * (float)n_in;
  else if (K <= 0 || KD % K != 0)         sig = 2.5e7f;
  else if (D != 64)                       sig = 1e7f + 1e4f * (float)D;
  else if (KD2 != KD)                     sig = 2e7f;
  else if (ND % 64 != 0 || N % 512 != 0)  sig = 3e7f;
  else if (K % 256 != 0)                  sig = 5e7f;
  else if (N < 2 * K)                     sig = 6e7f;  // rowlist+offs+cursor fit in slots
  else if ((long long)out_size != ND + 1 + N + K + 2 * KD)
                                          sig = (float)out_size;
  else if (ws_size < (size_t)ws_floats * sizeof(float))
                                          sig = 7e6f;
  if (sig != 0.f) { k_sig<<<1, 1, 0, stream>>>(o, sig); return; }

  u64* slots = (u64*)(ws + 16 + 2 * K + KD);      // 8-byte aligned offset
  u32* scratch = (u32*)slots;                     // reused AFTER k_post
  u32* rowlist = scratch;                         // [0, N)
  u32* offs    = scratch + N;                     // [N, N+K)
  u32* cursor  = scratch + N + K;                 // [N+K, N+2K)
  float* counts = ws + WS_HDR + K;
  float* embsum = ws + WS_HDR + 2 * K;
  const float lossmul = (float)(0.25 / (double)ND);

  hipMemsetAsync(ws, 0, (size_t)(16 + 2 * K + KD) * sizeof(float), stream);
  hipMemsetAsync(slots, 0xFF, (size_t)N * sizeof(u64), stream);
  k_prep<<<(int)(K / 256), 256, 0, stream>>>(cb, ecs, ws, (int)K);
  k_main<<<(int)(N / 128), 256, 0, stream>>>(z, cb, ws + WS_HDR, slots, (int)N, (int)K);
  k_post<<<(int)(N / 256), 256, 0, stream>>>(z, cb, slots, ws, o, (int)N, (int)K);
  k_scan<<<1, 256, 0, stream>>>(counts, offs, cursor, (int)K);
  k_scat<<<(int)(N / 256), 256, 0, stream>>>(o + ((size_t)N << 6) + 1, cursor, rowlist, (int)N);
  k_emb<<<(int)(K / 4), 256, 0, stream>>>(z, counts, offs, rowlist, embsum, (int)K);
  k_fin<<<(int)(KD / 256), 256, 0, stream>>>(ecs, ees, ws, o, (int)N, (int)K, lossmul);
}

// Round 12
// 529.359 us; speedup vs baseline: 2.6634x; 1.7806x over previous
//
#include <hip/hip_runtime.h>
#include <stdint.h>

typedef float4 __attribute__((may_alias)) float4a;
typedef uint4  __attribute__((may_alias)) uint4a;
typedef unsigned int u32;
typedef unsigned short u16;
typedef unsigned long long u64;
typedef __attribute__((ext_vector_type(8)))  short bf16x8;   // 4 VGPRs = 8 bf16
typedef __attribute__((ext_vector_type(16))) float f32x16;   // 32x32 accumulator

// ws float layout: [0] loss, [1] sum(ema_cs),
// [16,16+K) e2 | [16+K,+K) counts | [16+2K,+K*64) emb sums | then N u64 slots
// slots region reused AFTER k_post as u32: rowlist | offs | cursor
// o[0, 96K) floats reused BEFORE k_post as bf16-split codebook scratch (eh|em|el)
#define WS_LOSS 0
#define WS_SEMA 1
#define WS_HDR  16

__global__ void k_sig(float* o, float v) { o[0] = v; }

__device__ __forceinline__ float sq_nofuse(float x) {
  float p = x * x;
  __asm__("" : "+v"(p));   // block ffp-contract fusing (numpy rounds the square)
  return p;
}

// numpy pairwise_sum of squares, n=64 contiguous fp32 (verbatim, np-exact)
__device__ __forceinline__ float z2_np64(const float* v) {
  float r0 = sq_nofuse(v[0]), r1 = sq_nofuse(v[1]);
  float r2 = sq_nofuse(v[2]), r3 = sq_nofuse(v[3]);
  float r4 = sq_nofuse(v[4]), r5 = sq_nofuse(v[5]);
  float r6 = sq_nofuse(v[6]), r7 = sq_nofuse(v[7]);
  #pragma unroll
  for (int i = 8; i < 64; i += 8) {
    r0 += sq_nofuse(v[i + 0]); r1 += sq_nofuse(v[i + 1]);
    r2 += sq_nofuse(v[i + 2]); r3 += sq_nofuse(v[i + 3]);
    r4 += sq_nofuse(v[i + 4]); r5 += sq_nofuse(v[i + 5]);
    r6 += sq_nofuse(v[i + 6]); r7 += sq_nofuse(v[i + 7]);
  }
  return ((r0 + r1) + (r2 + r3)) + ((r4 + r5) + (r6 + r7));
}

__device__ __forceinline__ u16 bf16rne(float f) {
  const u32 x = __float_as_uint(f);
  return (u16)((x + 0x7fffu + ((x >> 16) & 1u)) >> 16);
}
__device__ __forceinline__ float bfup(u16 h) { return __uint_as_float(((u32)h) << 16); }

// async 16B-per-lane DMA: global -> LDS (wave-uniform LDS base + lane*16)
__device__ __forceinline__ void dma16(const float* g, float* l) {
  __builtin_amdgcn_global_load_lds(
      (const __attribute__((address_space(1))) unsigned int*)g,
      (__attribute__((address_space(3))) unsigned int*)l,
      16, 0, 0);
}

// e2 + ecs-sum + 3-way bf16 split of codebook into o-scratch.
// Split layout per term: [code][slot'] where slot' = slot ^ (code&7), slot s
// holds k = s*8..s*8+7 packed as 4 dwords (lo|hi) -> matches B-fragment reads.
__global__ __launch_bounds__(256) void k_prep(const float* __restrict__ cb,
                                              const float* __restrict__ ecs,
                                              float* __restrict__ ws,
                                              float* __restrict__ osc, int K) {
  const int k = blockIdx.x * 256 + threadIdx.x;   // grid covers exactly K rows
  const float* e = cb + ((size_t)k << 6);
  ws[WS_HDR + k] = z2_np64(e);                    // e2[k], np-fp32-exact

  float v = ecs[k];
  #pragma unroll
  for (int o = 32; o; o >>= 1) v += __shfl_xor(v, o, 64);
  if ((threadIdx.x & 63) == 0) atomicAdd(&ws[WS_SEMA], v);

  u32* od = (u32*)osc;
  const u32 tstr = (u32)K * 32u;                  // term stride (dwords)
  const u32 cbase = (u32)k * 32u;
  #pragma unroll
  for (int s = 0; s < 8; ++s) {
    u32 dh[4], dm[4], dl[4];
    #pragma unroll
    for (int j = 0; j < 4; ++j) {
      const float f0 = e[s * 8 + 2 * j], f1 = e[s * 8 + 2 * j + 1];
      const u16 h0 = bf16rne(f0), h1 = bf16rne(f1);
      const float r0 = f0 - bfup(h0), r1 = f1 - bfup(h1);
      const u16 m0 = bf16rne(r0), m1 = bf16rne(r1);
      const float q0 = r0 - bfup(m0), q1 = r1 - bfup(m1);
      dh[j] = (u32)h0 | ((u32)h1 << 16);
      dm[j] = (u32)m0 | ((u32)m1 << 16);
      dl[j] = (u32)bf16rne(q0) | ((u32)bf16rne(q1) << 16);
    }
    const u32 sp = (u32)(s ^ (k & 7)) * 4u;
    *(uint4a*)(od + cbase + sp)             = make_uint4(dh[0], dh[1], dh[2], dh[3]);
    *(uint4a*)(od + tstr + cbase + sp)      = make_uint4(dm[0], dm[1], dm[2], dm[3]);
    *(uint4a*)(od + 2 * tstr + cbase + sp)  = make_uint4(dl[0], dl[1], dl[2], dl[3]);
  }
}

// MFMA distance scan: block = 128 rows (4 waves x 32), 64-code e-tiles dbuf'd.
// g via 6 bf16-split MFMA products into fp32 acc (error ~fp32-ulp, ~= current
// chain's own deviation from BLAS order, which yields zero index flips).
// A-frags (z-splits) built in registers once; B-frags ds_read_b128 from LDS.
__global__ __launch_bounds__(256) void k_main(const float* __restrict__ z,
                                              const float* __restrict__ osc,
                                              const float* __restrict__ e2s,
                                              u64* __restrict__ slots,
                                              int N, int K) {
  __shared__ u32 ebuf[2][6208];        // [eh|em|el] 3x2048 dw + e2 64 dw
  __shared__ float z2p[128][4];

  const int tid  = threadIdx.x;
  const int lane = tid & 63;
  const int w    = tid >> 6;
  const int l31  = lane & 31;
  const int hK   = lane >> 5;          // k-half selector (A/B layout)
  const int rowbase = blockIdx.x * 128;
  const int nt   = K >> 6;             // 64-code tiles
  const u32 tstr = (u32)K * 32u;

  // ---- z2 partials (verbatim R8-R11, np-tree-exact)
  {
    const int sc = tid & 127;
    const int h  = tid >> 7;
    const float* vr = z + ((size_t)(rowbase + sc) << 6) + 4 * h;
    float ra = sq_nofuse(vr[0]), rb = sq_nofuse(vr[1]);
    float rc = sq_nofuse(vr[2]), rd = sq_nofuse(vr[3]);
    #pragma unroll
    for (int i = 8; i < 64; i += 8) {
      ra += sq_nofuse(vr[i + 0]); rb += sq_nofuse(vr[i + 1]);
      rc += sq_nofuse(vr[i + 2]); rd += sq_nofuse(vr[i + 3]);
    }
    z2p[sc][2 * h + 0] = ra + rb;
    z2p[sc][2 * h + 1] = rc + rd;
  }

  // ---- A-fragments: zh/zm/zl x 4 ksteps for this lane's row
  // layout: row = lane&31, k = (lane>>5)*8 + i  (8 consecutive bf16)
  bf16x8 azh[4], azm[4], azl[4];
  {
    const int row = rowbase + (w << 5) + l31;
    const float* zr = z + ((size_t)row << 6) + (hK << 3);
    #pragma unroll
    for (int ks = 0; ks < 4; ++ks) {
      const float4 p0 = *(const float4a*)(zr + ks * 16);
      const float4 p1 = *(const float4a*)(zr + ks * 16 + 4);
      const float f[8] = {p0.x, p0.y, p0.z, p0.w, p1.x, p1.y, p1.z, p1.w};
      union { u32 d[4]; bf16x8 v; } uh, um, ul;
      #pragma unroll
      for (int j = 0; j < 4; ++j) {
        const float f0 = f[2 * j], f1 = f[2 * j + 1];
        const u16 h0 = bf16rne(f0), h1 = bf16rne(f1);
        const float r0 = f0 - bfup(h0), r1 = f1 - bfup(h1);
        const u16 m0 = bf16rne(r0), m1 = bf16rne(r1);
        const float q0 = r0 - bfup(m0), q1 = r1 - bfup(m1);
        uh.d[j] = (u32)h0 | ((u32)h1 << 16);
        um.d[j] = (u32)m0 | ((u32)m1 << 16);
        ul.d[j] = (u32)bf16rne(q0) | ((u32)bf16rne(q1) << 16);
      }
      azh[ks] = uh.v; azm[ks] = um.v; azl[ks] = ul.v;
    }
  }

  // ---- stage tile 0 (eh|em|el|e2) via global_load_lds
  #pragma unroll
  for (int i = 0; i < 6; ++i) {
    const int G0 = i * 256 + w * 64;
    const int term = G0 >> 9, gg0 = G0 & 511;
    dma16(osc + (size_t)term * tstr + (size_t)(gg0 + lane) * 4,
          (float*)&ebuf[0][G0 * 4]);
  }
  if (tid < 16) dma16(e2s + tid * 4, (float*)&ebuf[0][6144]);

  __syncthreads();                     // z2p ready + tile0 dma drained

  // per-lane row constants: rows (r&3) + 8*(r>>2) + 4*hK of this wave
  float z2l[16];
  #pragma unroll
  for (int r = 0; r < 16; ++r) {
    const int rib = (w << 5) + (r & 3) + ((r >> 2) << 3) + (hK << 2);
    const float4 p = *(const float4a*)&z2p[rib][0];
    z2l[r] = (p.x + p.y) + (p.z + p.w);
  }

  float best[16]; int bk[16];
  #pragma unroll
  for (int r = 0; r < 16; ++r) { best[r] = 3.0e38f; bk[r] = 0; }

  for (int t = 0; t < nt; ++t) {
    if (t > 0) __syncthreads();        // tile t dma drained; buf[(t+1)&1] readers done
    if (t + 1 < nt) {
      const int bb = (t + 1) & 1;
      #pragma unroll
      for (int i = 0; i < 6; ++i) {
        const int G0 = i * 256 + w * 64;
        const int term = G0 >> 9, gg0 = G0 & 511;
        dma16(osc + (size_t)term * tstr + (size_t)(t + 1) * 2048
                  + (size_t)(gg0 + lane) * 4,
              (float*)&ebuf[bb][G0 * 4]);
      }
      if (tid < 16) dma16(e2s + (t + 1) * 64 + tid * 4, (float*)&ebuf[bb][6144]);
    }

    const u32* eb = ebuf[t & 1];
    #pragma unroll
    for (int c2 = 0; c2 < 2; ++c2) {
      const int cc = (c2 << 5) | l31;        // code within tile (lane's column)
      const u32 cb32 = (u32)cc * 32u;
      f32x16 acc = {};
      #pragma unroll
      for (int ks = 0; ks < 4; ++ks) {
        const u32 sp = (u32)(((ks << 1) | hK) ^ (lane & 7)) * 4u;
        const bf16x8 beh = *(const bf16x8*)(eb + cb32 + sp);
        const bf16x8 bem = *(const bf16x8*)(eb + 2048 + cb32 + sp);
        const bf16x8 bel = *(const bf16x8*)(eb + 4096 + cb32 + sp);
        acc = __builtin_amdgcn_mfma_f32_32x32x16_bf16(azh[ks], beh, acc, 0, 0, 0);
        acc = __builtin_amdgcn_mfma_f32_32x32x16_bf16(azm[ks], beh, acc, 0, 0, 0);
        acc = __builtin_amdgcn_mfma_f32_32x32x16_bf16(azl[ks], beh, acc, 0, 0, 0);
        acc = __builtin_amdgcn_mfma_f32_32x32x16_bf16(azh[ks], bem, acc, 0, 0, 0);
        acc = __builtin_amdgcn_mfma_f32_32x32x16_bf16(azm[ks], bem, acc, 0, 0, 0);
        acc = __builtin_amdgcn_mfma_f32_32x32x16_bf16(azh[ks], bel, acc, 0, 0, 0);
      }
      // selection: lane's codes strictly ascend across (t, c2) -> first-min-wins
      const float e2c = ((const float*)(eb + 6144))[cc];
      const int kg = (t << 6) + cc;
      #pragma unroll
      for (int r = 0; r < 16; ++r) {
        const float d = __builtin_fmaf(-2.0f, acc[r], z2l[r] + e2c);
        if (d < best[r]) { best[r] = d; bk[r] = kg; }
      }
    }
  }

  // ---- cross-lane merge over 32 columns (lex (d,k): equal d -> smaller k)
  #pragma unroll
  for (int off = 1; off <= 16; off <<= 1) {
    #pragma unroll
    for (int r = 0; r < 16; ++r) {
      const float pd = __shfl_xor(best[r], off, 64);
      const int   pk = __shfl_xor(bk[r], off, 64);
      if (pd < best[r] || (pd == best[r] && pk < bk[r])) { best[r] = pd; bk[r] = pk; }
    }
  }
  // ---- cross-wave/block merge via packed atomicMin (distances > 0)
  if (l31 == 0) {
    #pragma unroll
    for (int r = 0; r < 16; ++r) {
      const int row = rowbase + (w << 5) + (r & 3) + ((r >> 2) << 3) + (hK << 2);
      atomicMin(&slots[row],
                ((u64)__float_as_uint(best[r]) << 32) | (u32)bk[r]);
    }
  }
}

// epilogue: read winner, write index+quantized, loss, counts (NO emb atomics)
__global__ __launch_bounds__(256) void k_post(const float* __restrict__ z,
                                              const float* __restrict__ cb,
                                              const u64* __restrict__ slots,
                                              float* __restrict__ ws,
                                              float* __restrict__ o,
                                              int N, int K) {
  const int r = blockIdx.x * 256 + threadIdx.x;
  const int bk = (int)(u32)(slots[r] & 0xFFFFFFFFull);
  const size_t base = (size_t)N << 6;
  o[base + 1 + (size_t)r] = (float)bk;

  const float4a* zr = (const float4a*)(z + ((size_t)r << 6));
  const float4a* qr = (const float4a*)(cb + ((size_t)bk << 6));
  float4a* dst = (float4a*)(o + ((size_t)r << 6));
  float lsum = 0.f;
  #pragma unroll
  for (int t = 0; t < 16; ++t) {
    const float4 zw = zr[t];
    const float4 qw = qr[t];
    float4 out;
    float d;
    d = zw.x - qw.x; lsum = __builtin_fmaf(d, d, lsum); out.x = zw.x + (qw.x - zw.x);
    d = zw.y - qw.y; lsum = __builtin_fmaf(d, d, lsum); out.y = zw.y + (qw.y - zw.y);
    d = zw.z - qw.z; lsum = __builtin_fmaf(d, d, lsum); out.z = zw.z + (qw.z - zw.z);
    d = zw.w - qw.w; lsum = __builtin_fmaf(d, d, lsum); out.w = zw.w + (qw.w - zw.w);
    dst[t] = out;
  }

  #pragma unroll
  for (int s = 32; s; s >>= 1) lsum += __shfl_xor(lsum, s, 64);
  if ((threadIdx.x & 63) == 0) atomicAdd(ws + WS_LOSS, lsum);

  atomicAdd(ws + WS_HDR + K + bk, 1.0f);   // counts only
}

// exclusive prefix-sum of counts -> offs, cursor (1 block)
__global__ __launch_bounds__(256) void k_scan(const float* __restrict__ counts,
                                              u32* __restrict__ offs,
                                              u32* __restrict__ cursor, int K) {
  __shared__ u32 part[256];
  const int tid = threadIdx.x;
  const int per = K >> 8;
  const int b0 = tid * per;
  u32 s = 0;
  for (int i = 0; i < per; ++i) s += (u32)counts[b0 + i];
  part[tid] = s;
  __syncthreads();
  if (tid == 0) {
    u32 run = 0;
    for (int i = 0; i < 256; ++i) { const u32 v = part[i]; part[i] = run; run += v; }
  }
  __syncthreads();
  u32 run = part[tid];
  for (int i = 0; i < per; ++i) {
    offs[b0 + i] = run;
    cursor[b0 + i] = run;
    run += (u32)counts[b0 + i];
  }
}

// scatter row ids into per-code buckets
__global__ __launch_bounds__(256) void k_scat(const float* __restrict__ idxs,
                                              u32* __restrict__ cursor,
                                              u32* __restrict__ rowlist, int N) {
  const int r = blockIdx.x * 256 + threadIdx.x;
  const int bk = (int)idxs[r];
  const u32 pos = atomicAdd(&cursor[bk], 1u);
  rowlist[pos] = (u32)r;
}

// per-code gather sum: one wave per code, lane j sums column j. Plain store.
__global__ __launch_bounds__(256) void k_emb(const float* __restrict__ z,
                                             const float* __restrict__ counts,
                                             const u32* __restrict__ offs,
                                             const u32* __restrict__ rowlist,
                                             float* __restrict__ emb, int K) {
  const int lane = threadIdx.x & 63;
  const int k = blockIdx.x * 4 + (threadIdx.x >> 6);
  const u32 off = offs[k];
  const u32 cnt = (u32)counts[k];
  float sum = 0.f;
  u32 i = 0;
  for (; i + 4 <= cnt; i += 4) {
    const u32 r0 = rowlist[off + i + 0];
    const u32 r1 = rowlist[off + i + 1];
    const u32 r2 = rowlist[off + i + 2];
    const u32 r3 = rowlist[off + i + 3];
    const float a0 = z[((size_t)r0 << 6) + lane];
    const float a1 = z[((size_t)r1 << 6) + lane];
    const float a2 = z[((size_t)r2 << 6) + lane];
    const float a3 = z[((size_t)r3 << 6) + lane];
    sum = (((sum + a0) + a1) + a2) + a3;
  }
  for (; i < cnt; ++i) {
    const u32 r0 = rowlist[off + i];
    sum += z[((size_t)r0 << 6) + lane];
  }
  emb[((size_t)k << 6) + lane] = sum;
}

__global__ __launch_bounds__(256) void k_fin(const float* __restrict__ ecs,
                                             const float* __restrict__ ees,
                                             const float* __restrict__ ws,
                                             float* __restrict__ o,
                                             int N, int K, float lossmul) {
  const int KD = K << 6;
  const int idx = blockIdx.x * 256 + threadIdx.x;
  if (idx >= KD) return;
  const int k = idx >> 6;
  const int j = idx & 63;
  const size_t base = (size_t)N << 6;

  const float n = 0.99f * ws[WS_SEMA] + 0.01f * (float)N;
  const float cs_new = 0.99f * ecs[k] + 0.01f * ws[WS_HDR + K + k];
  const float smoothed = (cs_new + 1e-5f) / (n + (float)K * 1e-5f) * n;
  const float es_new = 0.99f * ees[idx] + 0.01f * ws[WS_HDR + 2 * K + idx];

  const size_t es_base = base + 1 + (size_t)N + (size_t)K;
  o[es_base + (size_t)idx] = es_new;
  o[es_base + (size_t)KD + (size_t)idx] = es_new / smoothed;
  if (j == 0)   o[base + 1 + (size_t)N + (size_t)k] = cs_new;
  if (idx == 0) o[base] = ws[WS_LOSS] * lossmul;
}

extern "C" void kernel_launch(void* const* d_in, const int* in_sizes, int n_in,
                              void* d_out, int out_size, void* d_ws, size_t ws_size,
                              hipStream_t stream) {
  float* o = (float*)d_out;
  const float* z   = (const float*)d_in[0];
  const float* cb  = (const float*)d_in[1];
  const float* ecs = (const float*)d_in[2];
  const float* ees = (const float*)d_in[3];
  float* ws = (float*)d_ws;

  const long long ND  = (n_in > 0) ? (long long)in_sizes[0] : 0;
  const long long KD  = (n_in > 1) ? (long long)in_sizes[1] : 0;
  const long long K   = (n_in > 2) ? (long long)in_sizes[2] : 0;
  const long long KD2 = (n_in > 3) ? (long long)in_sizes[3] : 0;
  const long long D   = (K > 0) ? KD / K : 0;
  const long long N   = (D > 0) ? ND / D : 0;

  const long long ws_floats = 16 + 2 * K + KD + 2 * N;  // slots = N u64 at tail

  float sig = 0.f;
  if (n_in != 4)                          sig = 1e4f * (float)n_in;
  else if (K <= 0 || KD % K != 0)         sig = 2.5e7f;
  else if (D != 64)                       sig = 1e7f + 1e4f * (float)D;
  else if (KD2 != KD)                     sig = 2e7f;
  else if (ND % 64 != 0 || N % 512 != 0)  sig = 3e7f;
  else if (K % 256 != 0)                  sig = 5e7f;
  else if (N < 2 * K)                     sig = 6e7f;  // scatter scratch fits in slots
  else if (ND < 96 * K)                   sig = 8e6f;  // split scratch fits in o
  else if ((long long)out_size != ND + 1 + N + K + 2 * KD)
                                          sig = (float)out_size;
  else if (ws_size < (size_t)ws_floats * sizeof(float))
                                          sig = 7e6f;
  if (sig != 0.f) { k_sig<<<1, 1, 0, stream>>>(o, sig); return; }

  u64* slots = (u64*)(ws + 16 + 2 * K + KD);      // 8-byte aligned offset
  u32* scratch = (u32*)slots;                     // reused AFTER k_post
  u32* rowlist = scratch;                         // [0, N)
  u32* offs    = scratch + N;                     // [N, N+K)
  u32* cursor  = scratch + N + K;                 // [N+K, N+2K)
  float* counts = ws + WS_HDR + K;
  float* embsum = ws + WS_HDR + 2 * K;
  const float lossmul = (float)(0.25 / (double)ND);

  hipMemsetAsync(ws, 0, (size_t)(16 + 2 * K + KD) * sizeof(float), stream);
  hipMemsetAsync(slots, 0xFF, (size_t)N * sizeof(u64), stream);
  k_prep<<<(int)(K / 256), 256, 0, stream>>>(cb, ecs, ws, o, (int)K);
  k_main<<<(int)(N / 128), 256, 0, stream>>>(z, o, ws + WS_HDR, slots, (int)N, (int)K);
  k_post<<<(int)(N / 256), 256, 0, stream>>>(z, cb, slots, ws, o, (int)N, (int)K);
  k_scan<<<1, 256, 0, stream>>>(counts, offs, cursor, (int)K);
  k_scat<<<(int)(N / 256), 256, 0, stream>>>(o + ((size_t)N << 6) + 1, cursor, rowlist, (int)N);
  k_emb<<<(int)(K / 4), 256, 0, stream>>>(z, counts, offs, rowlist, embsum, (int)K);
  k_fin<<<(int)(KD / 256), 256, 0, stream>>>(ecs, ees, ws, o, (int)N, (int)K, lossmul);
}